// Round 3
// baseline (847.559 us; speedup 1.0000x reference)
//
#include <hip/hip_runtime.h>
#include <hip/hip_bf16.h>

typedef __bf16 bf16x8 __attribute__((ext_vector_type(8)));
typedef float  f32x4  __attribute__((ext_vector_type(4)));
typedef float  f32x8  __attribute__((ext_vector_type(8)));
typedef unsigned int uint32_t_;

#define EPSV 1e-5f

// ---------------------------------------------------------------------------
// K1: A = x @ Wa^T, B = x @ Wb^T, fused per-channel sum/sumsq atomics.
// grid 256 x 256; block does 4 rows of x.
// gs: [sumA|sumsqA|sumB|sumsqB] (pre-zeroed), 512 floats.
// ---------------------------------------------------------------------------
__global__ __launch_bounds__(256) void k_ab(const float* __restrict__ x,
                                            const float* __restrict__ W1,
                                            float* __restrict__ A,
                                            float* __restrict__ Bm,
                                            float* __restrict__ gs) {
  __shared__ float xs[4 * 128];
  int t = threadIdx.x;
  int j0 = blockIdx.x * 4;
  for (int idx = t; idx < 512; idx += 256) xs[idx] = x[j0 * 128 + idx];
  __syncthreads();
  int h = t & 127, half = t >> 7;
  const float4* wrow = (const float4*)(W1 + h * 256 + half * 128);
  const float4* xs4 = (const float4*)xs;
  float a0 = 0.f, a1 = 0.f, a2 = 0.f, a3 = 0.f;
#pragma unroll 8
  for (int ch = 0; ch < 32; ++ch) {
    float4 wv = wrow[ch];
    float4 x0 = xs4[ch], x1 = xs4[32 + ch], x2 = xs4[64 + ch], x3 = xs4[96 + ch];
    a0 += wv.x * x0.x + wv.y * x0.y + wv.z * x0.z + wv.w * x0.w;
    a1 += wv.x * x1.x + wv.y * x1.y + wv.z * x1.z + wv.w * x1.w;
    a2 += wv.x * x2.x + wv.y * x2.y + wv.z * x2.z + wv.w * x2.w;
    a3 += wv.x * x3.x + wv.y * x3.y + wv.z * x3.z + wv.w * x3.w;
  }
  float* dst = half ? Bm : A;
  dst[(j0 + 0) * 128 + h] = a0;
  dst[(j0 + 1) * 128 + h] = a1;
  dst[(j0 + 2) * 128 + h] = a2;
  dst[(j0 + 3) * 128 + h] = a3;
  float s = a0 + a1 + a2 + a3;
  float q = a0 * a0 + a1 * a1 + a2 * a2 + a3 * a3;
  atomicAdd(&gs[half * 256 + h], s);
  atomicAdd(&gs[half * 256 + 128 + h], q);
}

// ---------------------------------------------------------------------------
// K2: W2 f32 -> bf16, permuted into MFMA-fragment order (parallel).
// chunk c (4B, 2 elems): c = (((ks*8+nt)*16+col)*4+quad)*4+pair
// elem: k = nt*16+col, hch = ks*32+quad*8+pair*2
// grid 32 x 256.
// ---------------------------------------------------------------------------
__global__ __launch_bounds__(256) void k_w2prep(const float* __restrict__ W2,
                                                unsigned int* __restrict__ w2p) {
  int c = blockIdx.x * 256 + threadIdx.x;  // 0..8191
  int pair = c & 3;
  int quad = (c >> 2) & 3;
  int col  = (c >> 4) & 15;
  int nt   = (c >> 8) & 7;
  int ks   = (c >> 11) & 3;
  int k = nt * 16 + col;
  int hch = ks * 32 + quad * 8 + pair * 2;
  float v0 = W2[k * 128 + hch];
  float v1 = W2[k * 128 + hch + 1];
  __bf16 b0 = (__bf16)v0, b1 = (__bf16)v1;
  unsigned int u0 = *(unsigned short*)&b0, u1 = *(unsigned short*)&b1;
  w2p[c] = u0 | (u1 << 16);
}

// ---------------------------------------------------------------------------
// K3: BN1 fold (recomputed per block in LDS) + apply:
// At = A*sc+ta, Bt = B*sc+tb. grid 128 x 256 (float4 each).
// ---------------------------------------------------------------------------
__global__ __launch_bounds__(256) void k_fold_apply(const float* __restrict__ gs,
                                                    const float* __restrict__ g1,
                                                    const float* __restrict__ be1,
                                                    const float* __restrict__ A,
                                                    const float* __restrict__ Bm,
                                                    float* __restrict__ At,
                                                    float* __restrict__ Bt) {
  __shared__ float sc_s[128], ta_s[128], tb_s[128];
  int t = threadIdx.x;
  if (t < 128) {
    const float inv = 1.f / 1024.f;
    float mA = gs[t] * inv;
    float vA = gs[128 + t] * inv - mA * mA;
    float mB = gs[256 + t] * inv;
    float vB = gs[384 + t] * inv - mB * mB;
    float sc = g1[t] * rsqrtf(vA + vB + EPSV);
    sc_s[t] = sc;
    ta_s[t] = be1[t] - mA * sc;
    tb_s[t] = -mB * sc;
  }
  __syncthreads();
  int idx4 = blockIdx.x * 256 + t;
  int c4 = idx4 & 31;
  float4 sc = ((const float4*)sc_s)[c4];
  float4 ta = ((const float4*)ta_s)[c4];
  float4 tb = ((const float4*)tb_s)[c4];
  float4 a = ((const float4*)A)[idx4];
  float4 b = ((const float4*)Bm)[idx4];
  float4 oa, ob;
  oa.x = fmaf(a.x, sc.x, ta.x); oa.y = fmaf(a.y, sc.y, ta.y);
  oa.z = fmaf(a.z, sc.z, ta.z); oa.w = fmaf(a.w, sc.w, ta.w);
  ob.x = fmaf(b.x, sc.x, tb.x); ob.y = fmaf(b.y, sc.y, tb.y);
  ob.z = fmaf(b.z, sc.z, tb.z); ob.w = fmaf(b.w, sc.w, tb.w);
  ((float4*)At)[idx4] = oa;
  ((float4*)Bt)[idx4] = ob;
}

// ---------------------------------------------------------------------------
// h1 A-fragment built in registers: relu(At[j][k]+Bt[i][k]), k=off..off+8.
// ---------------------------------------------------------------------------
__device__ __forceinline__ bf16x8 build_h1(const float* __restrict__ arow,
                                           const float* __restrict__ brow,
                                           int off) {
  f32x4 a0 = *(const f32x4*)(arow + off);
  f32x4 a1 = *(const f32x4*)(arow + off + 4);
  f32x4 b0 = *(const f32x4*)(brow + off);
  f32x4 b1 = *(const f32x4*)(brow + off + 4);
  f32x4 z = {0.f, 0.f, 0.f, 0.f};
  f32x4 h0 = __builtin_elementwise_max(a0 + b0, z);
  f32x4 h1 = __builtin_elementwise_max(a1 + b1, z);
  f32x8 h = __builtin_shufflevector(h0, h1, 0, 1, 2, 3, 4, 5, 6, 7);
  return __builtin_convertvector(h, bf16x8);
}

// ---------------------------------------------------------------------------
// Main pass. W2 fragments staged to LDS (32 KB) via global_load_lds, read
// per-use with contiguous ds_read_b128. A-fragments built in registers.
// Block = 4 waves; wave w: i-rows {bi*8+2w, +1}, j: bj*128..+128 (8 subtiles).
// grid 1024 = bi(128) x bj(8). __launch_bounds__(256,4): 4 waves/SIMD.
// ---------------------------------------------------------------------------
template <int PASS>
__global__ __launch_bounds__(256, 4) void k_pass(
    const float* __restrict__ At, const float* __restrict__ Bt,
    const unsigned int* __restrict__ w2p, float* __restrict__ partials,
    const float* __restrict__ a2p, const float* __restrict__ W3v,
    const float* __restrict__ b3p, float* __restrict__ L) {
  __shared__ __bf16 w2s[16384];  // 32 KB
  __shared__ float red[1024];
  int t = threadIdx.x;
  int bid = blockIdx.x;
  int bj = bid & 7, bi = bid >> 3;
  int lane = t & 63, w = t >> 6;
  int col = lane & 15, quad = lane >> 4;

  // ---- stage permuted W2 into LDS: 2048 chunks x 16 B, 8 iters x 256 thr ----
#pragma unroll
  for (int it = 0; it < 8; ++it) {
    int chunk = it * 256 + t;
    __builtin_amdgcn_global_load_lds(
        (const __attribute__((address_space(1))) unsigned int*)(w2p + chunk * 4),
        (__attribute__((address_space(3))) unsigned int*)(w2s + (it * 4 + w) * 512),
        16, 0, 0);
  }
  __syncthreads();

  const float* brow0 = Bt + (bi * 8 + w * 2) * 128;
  const float* brow1 = brow0 + 128;
  const float* acol  = At + (bj * 128 + col) * 128;

  float s1[8], s2[8];
  float al[8], uu[8], w3l[8];
  float b3v = 0.f;
  if (PASS == 1) {
#pragma unroll
    for (int nt = 0; nt < 8; ++nt) { s1[nt] = 0.f; s2[nt] = 0.f; }
  } else {
    b3v = b3p[0];
#pragma unroll
    for (int nt = 0; nt < 8; ++nt) {
      int k = nt * 16 + col;
      al[nt] = a2p[k];
      uu[nt] = a2p[128 + k];
      w3l[nt] = W3v[k];
    }
  }

  for (int s = 0; s < 8; ++s) {
    const float* arow = acol + s * 16 * 128;
    f32x4 acc[2][8];
#pragma unroll
    for (int mt = 0; mt < 2; ++mt)
#pragma unroll
      for (int nt = 0; nt < 8; ++nt) acc[mt][nt] = (f32x4){0.f, 0.f, 0.f, 0.f};

#pragma unroll
    for (int ks = 0; ks < 4; ++ks) {
      int off = ks * 32 + quad * 8;
      bf16x8 a0 = build_h1(arow, brow0, off);
      bf16x8 a1 = build_h1(arow, brow1, off);
#pragma unroll
      for (int nt = 0; nt < 8; ++nt) {
        bf16x8 bv = *(const bf16x8*)(w2s + ((ks * 8 + nt) * 64 + col * 4 + quad) * 8);
        acc[0][nt] = __builtin_amdgcn_mfma_f32_16x16x32_bf16(a0, bv, acc[0][nt], 0, 0, 0);
        acc[1][nt] = __builtin_amdgcn_mfma_f32_16x16x32_bf16(a1, bv, acc[1][nt], 0, 0, 0);
      }
    }

    if (PASS == 1) {
#pragma unroll
      for (int nt = 0; nt < 8; ++nt)
#pragma unroll
        for (int mt = 0; mt < 2; ++mt)
#pragma unroll
          for (int r = 0; r < 4; ++r) {
            float d = acc[mt][nt][r];
            s1[nt] += d;
            s2[nt] = fmaf(d, d, s2[nt]);
          }
    } else {
#pragma unroll
      for (int mt = 0; mt < 2; ++mt) {
        float rsum[4] = {0.f, 0.f, 0.f, 0.f};
#pragma unroll
        for (int nt = 0; nt < 8; ++nt)
#pragma unroll
          for (int r = 0; r < 4; ++r) {
            float h = fmaxf(fmaf(acc[mt][nt][r], al[nt], uu[nt]), 0.f);
            rsum[r] = fmaf(h, w3l[nt], rsum[r]);
          }
#pragma unroll
        for (int r = 0; r < 4; ++r) {
          rsum[r] += __shfl_xor(rsum[r], 1);
          rsum[r] += __shfl_xor(rsum[r], 2);
          rsum[r] += __shfl_xor(rsum[r], 4);
          rsum[r] += __shfl_xor(rsum[r], 8);
        }
        if (col == 0) {
          int i = bi * 8 + w * 2 + mt;
#pragma unroll
          for (int r = 0; r < 4; ++r)
            L[i * 1024 + bj * 128 + s * 16 + quad * 4 + r] = rsum[r] + b3v;
        }
      }
    }
  }

  if (PASS == 1) {
#pragma unroll
    for (int nt = 0; nt < 8; ++nt) {
      s1[nt] += __shfl_xor(s1[nt], 16);
      s1[nt] += __shfl_xor(s1[nt], 32);
      s2[nt] += __shfl_xor(s2[nt], 16);
      s2[nt] += __shfl_xor(s2[nt], 32);
    }
    if (lane < 16) {
#pragma unroll
      for (int nt = 0; nt < 8; ++nt) {
        red[w * 256 + nt * 16 + lane] = s1[nt];
        red[w * 256 + 128 + nt * 16 + lane] = s2[nt];
      }
    }
    __syncthreads();
    float tot = red[t] + red[256 + t] + red[512 + t] + red[768 + t];
    partials[bid * 256 + t] = tot;
  }
}

// ---------------------------------------------------------------------------
// K5a: reduce pass-1 partials (1024 x 256) -> sum2[256]. grid 64 x 256.
// ---------------------------------------------------------------------------
__global__ __launch_bounds__(256) void k_red_partials(const float* __restrict__ partials,
                                                      float* __restrict__ sum2) {
  int t = threadIdx.x;
  float s = 0.f;
  int r0 = blockIdx.x * 16;
#pragma unroll
  for (int r = 0; r < 16; ++r) s += partials[(r0 + r) * 256 + t];
  atomicAdd(&sum2[t], s);
}

// ---------------------------------------------------------------------------
// K5b: BN2 fold params. a2p: [alpha2 | u2]. 1 block x 128 thr.
// ---------------------------------------------------------------------------
__global__ void k_fold2(const float* __restrict__ sum2, const float* __restrict__ g2,
                        const float* __restrict__ be2, float* __restrict__ a2p) {
  int k = threadIdx.x;
  const float invM = 1.f / (1024.f * 1024.f);
  float mdot = sum2[k] * invM;
  float var = sum2[128 + k] * invM - mdot * mdot;
  float al = g2[k] * rsqrtf(var + EPSV);
  a2p[k] = al;
  a2p[128 + k] = be2[k] - mdot * al;
}

// ---------------------------------------------------------------------------
// K7: adj[i,j] = (i==j) ? 0 : sigmoid(0.5*(L[i,j]+L[j,i])). grid 4096 x 256.
// ---------------------------------------------------------------------------
__global__ __launch_bounds__(256) void k_adj(const float* __restrict__ L,
                                             float* __restrict__ out) {
  int idx = blockIdx.x * 256 + threadIdx.x;
  int i = idx >> 10, j = idx & 1023;
  float a = L[i * 1024 + j];
  float b = L[j * 1024 + i];
  float s = 1.f / (1.f + __expf(-0.5f * (a + b)));
  out[idx] = (i == j) ? 0.f : s;
}

// ---------------------------------------------------------------------------
extern "C" void kernel_launch(void* const* d_in, const int* in_sizes, int n_in,
                              void* d_out, int out_size, void* d_ws, size_t ws_size,
                              hipStream_t stream) {
  const float* x   = (const float*)d_in[0];
  const float* W1  = (const float*)d_in[1];
  const float* W2  = (const float*)d_in[3];
  const float* W3  = (const float*)d_in[5];
  const float* b3  = (const float*)d_in[6];
  const float* g1  = (const float*)d_in[7];
  const float* be1 = (const float*)d_in[8];
  const float* g2  = (const float*)d_in[9];
  const float* be2 = (const float*)d_in[10];

  float* ws = (float*)d_ws;
  float* A        = ws;                 // 131072
  float* Bm       = ws + 131072;        // 131072
  float* At       = ws + 262144;        // 131072
  float* Bt       = ws + 393216;        // 131072
  unsigned int* w2p = (unsigned int*)(ws + 524288);  // 8192 uints
  float* gs       = ws + 532480;        // 512
  float* a2p      = ws + 533376;        // 256
  float* sum2     = ws + 533632;        // 256
  float* partials = ws + 533888;        // 1024*256
  float* L        = ws + 796032;        // 1048576
  float* out      = (float*)d_out;

  hipMemsetAsync(gs, 0, 512 * sizeof(float), stream);
  hipMemsetAsync(sum2, 0, 256 * sizeof(float), stream);

  k_ab<<<256, 256, 0, stream>>>(x, W1, A, Bm, gs);
  k_w2prep<<<32, 256, 0, stream>>>(W2, w2p);
  k_fold_apply<<<128, 256, 0, stream>>>(gs, g1, be1, A, Bm, At, Bt);
  k_pass<1><<<1024, 256, 0, stream>>>(At, Bt, w2p, partials, nullptr, nullptr, nullptr, nullptr);
  k_red_partials<<<64, 256, 0, stream>>>(partials, sum2);
  k_fold2<<<1, 128, 0, stream>>>(sum2, g2, be2, a2p);
  k_pass<2><<<1024, 256, 0, stream>>>(At, Bt, w2p, nullptr, a2p, W3, b3, L);
  k_adj<<<4096, 256, 0, stream>>>(L, out);
}

// Round 4
// 587.994 us; speedup vs baseline: 1.4414x; 1.4414x over previous
//
#include <hip/hip_runtime.h>
#include <hip/hip_bf16.h>

typedef __bf16 bf16x8 __attribute__((ext_vector_type(8)));
typedef float  f32x4  __attribute__((ext_vector_type(4)));
typedef float  f32x8  __attribute__((ext_vector_type(8)));

#define EPSV 1e-5f

// ---------------------------------------------------------------------------
// K1: A = x @ Wa^T, B = x @ Wb^T, fused per-channel sum/sumsq atomics.
// grid 256 x 256; block does 4 rows of x.
// gs: [sumA|sumsqA|sumB|sumsqB] (pre-zeroed), 512 floats.
// ---------------------------------------------------------------------------
__global__ __launch_bounds__(256) void k_ab(const float* __restrict__ x,
                                            const float* __restrict__ W1,
                                            float* __restrict__ A,
                                            float* __restrict__ Bm,
                                            float* __restrict__ gs) {
  __shared__ float xs[4 * 128];
  int t = threadIdx.x;
  int j0 = blockIdx.x * 4;
  for (int idx = t; idx < 512; idx += 256) xs[idx] = x[j0 * 128 + idx];
  __syncthreads();
  int h = t & 127, half = t >> 7;
  const float4* wrow = (const float4*)(W1 + h * 256 + half * 128);
  const float4* xs4 = (const float4*)xs;
  float a0 = 0.f, a1 = 0.f, a2 = 0.f, a3 = 0.f;
#pragma unroll 8
  for (int ch = 0; ch < 32; ++ch) {
    float4 wv = wrow[ch];
    float4 x0 = xs4[ch], x1 = xs4[32 + ch], x2 = xs4[64 + ch], x3 = xs4[96 + ch];
    a0 += wv.x * x0.x + wv.y * x0.y + wv.z * x0.z + wv.w * x0.w;
    a1 += wv.x * x1.x + wv.y * x1.y + wv.z * x1.z + wv.w * x1.w;
    a2 += wv.x * x2.x + wv.y * x2.y + wv.z * x2.z + wv.w * x2.w;
    a3 += wv.x * x3.x + wv.y * x3.y + wv.z * x3.z + wv.w * x3.w;
  }
  float* dst = half ? Bm : A;
  dst[(j0 + 0) * 128 + h] = a0;
  dst[(j0 + 1) * 128 + h] = a1;
  dst[(j0 + 2) * 128 + h] = a2;
  dst[(j0 + 3) * 128 + h] = a3;
  float s = a0 + a1 + a2 + a3;
  float q = a0 * a0 + a1 * a1 + a2 * a2 + a3 * a3;
  atomicAdd(&gs[half * 256 + h], s);
  atomicAdd(&gs[half * 256 + 128 + h], q);
}

// ---------------------------------------------------------------------------
// K2: W2 f32 -> bf16, permuted into MFMA-fragment order, unit-index = lane-id
// so ds_read_b128 is conflict-free (consecutive lanes -> consecutive 16B).
// 4B chunk c: c = ((ks*8+nt)*64 + quad*16 + col)*4 + pair
// elem: k_out = nt*16+col, hch = ks*32+quad*8+pair*2. grid 32 x 256.
// ---------------------------------------------------------------------------
__global__ __launch_bounds__(256) void k_w2prep(const float* __restrict__ W2,
                                                unsigned int* __restrict__ w2p) {
  int c = blockIdx.x * 256 + threadIdx.x;  // 0..8191
  int pair = c & 3;
  int col  = (c >> 2) & 15;
  int quad = (c >> 6) & 3;
  int nt   = (c >> 8) & 7;
  int ks   = (c >> 11) & 3;
  int k = nt * 16 + col;
  int hch = ks * 32 + quad * 8 + pair * 2;
  float v0 = W2[k * 128 + hch];
  float v1 = W2[k * 128 + hch + 1];
  __bf16 b0 = (__bf16)v0, b1 = (__bf16)v1;
  unsigned int u0 = *(unsigned short*)&b0, u1 = *(unsigned short*)&b1;
  w2p[c] = u0 | (u1 << 16);
}

// ---------------------------------------------------------------------------
// K3: BN1 fold (recomputed per block in LDS) + apply:
// At = A*sc+ta, Bt = B*sc+tb. grid 128 x 256 (float4 each).
// ---------------------------------------------------------------------------
__global__ __launch_bounds__(256) void k_fold_apply(const float* __restrict__ gs,
                                                    const float* __restrict__ g1,
                                                    const float* __restrict__ be1,
                                                    const float* __restrict__ A,
                                                    const float* __restrict__ Bm,
                                                    float* __restrict__ At,
                                                    float* __restrict__ Bt) {
  __shared__ float sc_s[128], ta_s[128], tb_s[128];
  int t = threadIdx.x;
  if (t < 128) {
    const float inv = 1.f / 1024.f;
    float mA = gs[t] * inv;
    float vA = gs[128 + t] * inv - mA * mA;
    float mB = gs[256 + t] * inv;
    float vB = gs[384 + t] * inv - mB * mB;
    float sc = g1[t] * rsqrtf(vA + vB + EPSV);
    sc_s[t] = sc;
    ta_s[t] = be1[t] - mA * sc;
    tb_s[t] = -mB * sc;
  }
  __syncthreads();
  int idx4 = blockIdx.x * 256 + t;
  int c4 = idx4 & 31;
  float4 sc = ((const float4*)sc_s)[c4];
  float4 ta = ((const float4*)ta_s)[c4];
  float4 tb = ((const float4*)tb_s)[c4];
  float4 a = ((const float4*)A)[idx4];
  float4 b = ((const float4*)Bm)[idx4];
  float4 oa, ob;
  oa.x = fmaf(a.x, sc.x, ta.x); oa.y = fmaf(a.y, sc.y, ta.y);
  oa.z = fmaf(a.z, sc.z, ta.z); oa.w = fmaf(a.w, sc.w, ta.w);
  ob.x = fmaf(b.x, sc.x, tb.x); ob.y = fmaf(b.y, sc.y, tb.y);
  ob.z = fmaf(b.z, sc.z, tb.z); ob.w = fmaf(b.w, sc.w, tb.w);
  ((float4*)At)[idx4] = oa;
  ((float4*)Bt)[idx4] = ob;
}

// ---------------------------------------------------------------------------
// h1 A-fragment built in registers: relu(At[j][k]+Bt[i][k]), k=off..off+8.
// ---------------------------------------------------------------------------
__device__ __forceinline__ bf16x8 build_h1(const float* __restrict__ arow,
                                           const float* __restrict__ brow,
                                           int off) {
  f32x4 a0 = *(const f32x4*)(arow + off);
  f32x4 a1 = *(const f32x4*)(arow + off + 4);
  f32x4 b0 = *(const f32x4*)(brow + off);
  f32x4 b1 = *(const f32x4*)(brow + off + 4);
  f32x4 z = {0.f, 0.f, 0.f, 0.f};
  f32x4 h0 = __builtin_elementwise_max(a0 + b0, z);
  f32x4 h1 = __builtin_elementwise_max(a1 + b1, z);
  f32x8 h = __builtin_shufflevector(h0, h1, 0, 1, 2, 3, 4, 5, 6, 7);
  return __builtin_convertvector(h, bf16x8);
}

// ---------------------------------------------------------------------------
// Main pass. W2 fragments staged to LDS (32 KB) via global_load_lds, read
// per-use with conflict-free ds_read_b128 (unit = lane). A-fragments built
// in registers. Block = 4 waves; wave w: i-rows {bi*8+2w,+1}, j: bj*128..+128.
// grid 1024 = bi(128) x bj(8). launch_bounds (256,3): no spill, >=3 w/SIMD.
// ---------------------------------------------------------------------------
template <int PASS>
__global__ __launch_bounds__(256, 3) void k_pass(
    const float* __restrict__ At, const float* __restrict__ Bt,
    const unsigned int* __restrict__ w2p, float* __restrict__ partials,
    const float* __restrict__ a2p, const float* __restrict__ W3v,
    const float* __restrict__ b3p, float* __restrict__ L) {
  __shared__ __bf16 w2s[16384];  // 32 KB
  __shared__ float red[1024];
  int t = threadIdx.x;
  int bid = blockIdx.x;
  int bj = bid & 7, bi = bid >> 3;
  int lane = t & 63, w = t >> 6;
  int col = lane & 15, quad = lane >> 4;

  // ---- stage permuted W2 into LDS: 2048 chunks x 16 B, 8 iters x 256 thr ----
#pragma unroll
  for (int it = 0; it < 8; ++it) {
    int chunk = it * 256 + t;
    __builtin_amdgcn_global_load_lds(
        (const __attribute__((address_space(1))) unsigned int*)(w2p + chunk * 4),
        (__attribute__((address_space(3))) unsigned int*)(w2s + (it * 4 + w) * 512),
        16, 0, 0);
  }
  __syncthreads();

  const float* brow0 = Bt + (bi * 8 + w * 2) * 128;
  const float* brow1 = brow0 + 128;
  const float* acol  = At + (bj * 128 + col) * 128;

  float s1[8], s2[8];
  float al[8], uu[8], w3l[8];
  float b3v = 0.f;
  if (PASS == 1) {
#pragma unroll
    for (int nt = 0; nt < 8; ++nt) { s1[nt] = 0.f; s2[nt] = 0.f; }
  } else {
    b3v = b3p[0];
#pragma unroll
    for (int nt = 0; nt < 8; ++nt) {
      int k = nt * 16 + col;
      al[nt] = a2p[k];
      uu[nt] = a2p[128 + k];
      w3l[nt] = W3v[k];
    }
  }

  for (int s = 0; s < 8; ++s) {
    const float* arow = acol + s * 16 * 128;
    f32x4 acc[2][8];
#pragma unroll
    for (int mt = 0; mt < 2; ++mt)
#pragma unroll
      for (int nt = 0; nt < 8; ++nt) acc[mt][nt] = (f32x4){0.f, 0.f, 0.f, 0.f};

#pragma unroll
    for (int ks = 0; ks < 4; ++ks) {
      int off = ks * 32 + quad * 8;
      bf16x8 a0 = build_h1(arow, brow0, off);
      bf16x8 a1 = build_h1(arow, brow1, off);
#pragma unroll
      for (int nt = 0; nt < 8; ++nt) {
        bf16x8 bv = *(const bf16x8*)(w2s + ((ks * 8 + nt) * 64 + quad * 16 + col) * 8);
        acc[0][nt] = __builtin_amdgcn_mfma_f32_16x16x32_bf16(a0, bv, acc[0][nt], 0, 0, 0);
        acc[1][nt] = __builtin_amdgcn_mfma_f32_16x16x32_bf16(a1, bv, acc[1][nt], 0, 0, 0);
      }
    }

    if (PASS == 1) {
#pragma unroll
      for (int nt = 0; nt < 8; ++nt)
#pragma unroll
        for (int mt = 0; mt < 2; ++mt)
#pragma unroll
          for (int r = 0; r < 4; ++r) {
            float d = acc[mt][nt][r];
            s1[nt] += d;
            s2[nt] = fmaf(d, d, s2[nt]);
          }
    } else {
#pragma unroll
      for (int mt = 0; mt < 2; ++mt) {
        float rsum[4] = {0.f, 0.f, 0.f, 0.f};
#pragma unroll
        for (int nt = 0; nt < 8; ++nt)
#pragma unroll
          for (int r = 0; r < 4; ++r) {
            float h = fmaxf(fmaf(acc[mt][nt][r], al[nt], uu[nt]), 0.f);
            rsum[r] = fmaf(h, w3l[nt], rsum[r]);
          }
#pragma unroll
        for (int r = 0; r < 4; ++r) {
          rsum[r] += __shfl_xor(rsum[r], 1);
          rsum[r] += __shfl_xor(rsum[r], 2);
          rsum[r] += __shfl_xor(rsum[r], 4);
          rsum[r] += __shfl_xor(rsum[r], 8);
        }
        if (col == 0) {
          int i = bi * 8 + w * 2 + mt;
#pragma unroll
          for (int r = 0; r < 4; ++r)
            L[i * 1024 + bj * 128 + s * 16 + quad * 4 + r] = rsum[r] + b3v;
        }
      }
    }
  }

  if (PASS == 1) {
#pragma unroll
    for (int nt = 0; nt < 8; ++nt) {
      s1[nt] += __shfl_xor(s1[nt], 16);
      s1[nt] += __shfl_xor(s1[nt], 32);
      s2[nt] += __shfl_xor(s2[nt], 16);
      s2[nt] += __shfl_xor(s2[nt], 32);
    }
    if (lane < 16) {
#pragma unroll
      for (int nt = 0; nt < 8; ++nt) {
        red[w * 256 + nt * 16 + lane] = s1[nt];
        red[w * 256 + 128 + nt * 16 + lane] = s2[nt];
      }
    }
    __syncthreads();
    float tot = red[t] + red[256 + t] + red[512 + t] + red[768 + t];
    partials[bid * 256 + t] = tot;
  }
}

// ---------------------------------------------------------------------------
// K5a: reduce pass-1 partials (1024 x 256) -> sum2[256]. grid 64 x 256.
// ---------------------------------------------------------------------------
__global__ __launch_bounds__(256) void k_red_partials(const float* __restrict__ partials,
                                                      float* __restrict__ sum2) {
  int t = threadIdx.x;
  float s = 0.f;
  int r0 = blockIdx.x * 16;
#pragma unroll
  for (int r = 0; r < 16; ++r) s += partials[(r0 + r) * 256 + t];
  atomicAdd(&sum2[t], s);
}

// ---------------------------------------------------------------------------
// K5b: BN2 fold params. a2p: [alpha2 | u2]. 1 block x 128 thr.
// ---------------------------------------------------------------------------
__global__ void k_fold2(const float* __restrict__ sum2, const float* __restrict__ g2,
                        const float* __restrict__ be2, float* __restrict__ a2p) {
  int k = threadIdx.x;
  const float invM = 1.f / (1024.f * 1024.f);
  float mdot = sum2[k] * invM;
  float var = sum2[128 + k] * invM - mdot * mdot;
  float al = g2[k] * rsqrtf(var + EPSV);
  a2p[k] = al;
  a2p[128 + k] = be2[k] - mdot * al;
}

// ---------------------------------------------------------------------------
// K7: adj[i,j] = (i==j) ? 0 : sigmoid(0.5*(L[i,j]+L[j,i])). grid 4096 x 256.
// ---------------------------------------------------------------------------
__global__ __launch_bounds__(256) void k_adj(const float* __restrict__ L,
                                             float* __restrict__ out) {
  int idx = blockIdx.x * 256 + threadIdx.x;
  int i = idx >> 10, j = idx & 1023;
  float a = L[i * 1024 + j];
  float b = L[j * 1024 + i];
  float s = 1.f / (1.f + __expf(-0.5f * (a + b)));
  out[idx] = (i == j) ? 0.f : s;
}

// ---------------------------------------------------------------------------
extern "C" void kernel_launch(void* const* d_in, const int* in_sizes, int n_in,
                              void* d_out, int out_size, void* d_ws, size_t ws_size,
                              hipStream_t stream) {
  const float* x   = (const float*)d_in[0];
  const float* W1  = (const float*)d_in[1];
  const float* W2  = (const float*)d_in[3];
  const float* W3  = (const float*)d_in[5];
  const float* b3  = (const float*)d_in[6];
  const float* g1  = (const float*)d_in[7];
  const float* be1 = (const float*)d_in[8];
  const float* g2  = (const float*)d_in[9];
  const float* be2 = (const float*)d_in[10];

  float* ws = (float*)d_ws;
  float* A        = ws;                 // 131072
  float* Bm       = ws + 131072;        // 131072
  float* At       = ws + 262144;        // 131072
  float* Bt       = ws + 393216;        // 131072
  unsigned int* w2p = (unsigned int*)(ws + 524288);  // 8192 uints
  float* gs       = ws + 532480;        // 512
  float* a2p      = ws + 533376;        // 256
  float* sum2     = ws + 533632;        // 256
  float* partials = ws + 533888;        // 1024*256
  float* L        = ws + 796032;        // 1048576
  float* out      = (float*)d_out;

  hipMemsetAsync(gs, 0, 512 * sizeof(float), stream);
  hipMemsetAsync(sum2, 0, 256 * sizeof(float), stream);

  k_ab<<<256, 256, 0, stream>>>(x, W1, A, Bm, gs);
  k_w2prep<<<32, 256, 0, stream>>>(W2, w2p);
  k_fold_apply<<<128, 256, 0, stream>>>(gs, g1, be1, A, Bm, At, Bt);
  k_pass<1><<<1024, 256, 0, stream>>>(At, Bt, w2p, partials, nullptr, nullptr, nullptr, nullptr);
  k_red_partials<<<64, 256, 0, stream>>>(partials, sum2);
  k_fold2<<<1, 128, 0, stream>>>(sum2, g2, be2, a2p);
  k_pass<2><<<1024, 256, 0, stream>>>(At, Bt, w2p, nullptr, a2p, W3, b3, L);
  k_adj<<<4096, 256, 0, stream>>>(L, out);
}

// Round 5
// 384.087 us; speedup vs baseline: 2.2067x; 1.5309x over previous
//
#include <hip/hip_runtime.h>
#include <hip/hip_bf16.h>

typedef __bf16 bf16x8 __attribute__((ext_vector_type(8)));
typedef float  f32x4  __attribute__((ext_vector_type(4)));
typedef float  f32x8  __attribute__((ext_vector_type(8)));

#define EPSV 1e-5f

// ---------------------------------------------------------------------------
// K1 (grid 288): blocks 0..255: A = x@Wa^T, B = x@Wb^T + stats atomics.
// blocks 256..287: W2 f32 -> bf16 permuted into MFMA B-fragment order:
//   4B chunk c = ((ks*8+nt)*64 + quad*16 + col)*4 + pair
//   elem: k_out = nt*16+col, hch = ks*32+quad*8+pair*2
// ---------------------------------------------------------------------------
__global__ __launch_bounds__(256) void k_ab(const float* __restrict__ x,
                                            const float* __restrict__ W1,
                                            const float* __restrict__ W2,
                                            float* __restrict__ A,
                                            float* __restrict__ Bm,
                                            float* __restrict__ gs,
                                            unsigned int* __restrict__ w2p) {
  __shared__ float xs[4 * 128];
  int t = threadIdx.x;
  if (blockIdx.x >= 256) {  // W2 prep
    int c = (blockIdx.x - 256) * 256 + t;  // 0..8191
    int pair = c & 3;
    int col  = (c >> 2) & 15;
    int quad = (c >> 6) & 3;
    int nt   = (c >> 8) & 7;
    int ks   = (c >> 11) & 3;
    int k = nt * 16 + col;
    int hch = ks * 32 + quad * 8 + pair * 2;
    __bf16 b0 = (__bf16)W2[k * 128 + hch];
    __bf16 b1 = (__bf16)W2[k * 128 + hch + 1];
    unsigned int u0 = *(unsigned short*)&b0, u1 = *(unsigned short*)&b1;
    w2p[c] = u0 | (u1 << 16);
    return;
  }
  int j0 = blockIdx.x * 4;
  for (int idx = t; idx < 512; idx += 256) xs[idx] = x[j0 * 128 + idx];
  __syncthreads();
  int h = t & 127, half = t >> 7;
  const float4* wrow = (const float4*)(W1 + h * 256 + half * 128);
  const float4* xs4 = (const float4*)xs;
  float a0 = 0.f, a1 = 0.f, a2 = 0.f, a3 = 0.f;
#pragma unroll 8
  for (int ch = 0; ch < 32; ++ch) {
    float4 wv = wrow[ch];
    float4 x0 = xs4[ch], x1 = xs4[32 + ch], x2 = xs4[64 + ch], x3 = xs4[96 + ch];
    a0 += wv.x * x0.x + wv.y * x0.y + wv.z * x0.z + wv.w * x0.w;
    a1 += wv.x * x1.x + wv.y * x1.y + wv.z * x1.z + wv.w * x1.w;
    a2 += wv.x * x2.x + wv.y * x2.y + wv.z * x2.z + wv.w * x2.w;
    a3 += wv.x * x3.x + wv.y * x3.y + wv.z * x3.z + wv.w * x3.w;
  }
  float* dst = half ? Bm : A;
  dst[(j0 + 0) * 128 + h] = a0;
  dst[(j0 + 1) * 128 + h] = a1;
  dst[(j0 + 2) * 128 + h] = a2;
  dst[(j0 + 3) * 128 + h] = a3;
  float s = a0 + a1 + a2 + a3;
  float q = a0 * a0 + a1 * a1 + a2 * a2 + a3 * a3;
  atomicAdd(&gs[half * 256 + h], s);
  atomicAdd(&gs[half * 256 + 128 + h], q);
}

// ---------------------------------------------------------------------------
// K2: BN1 fold (recomputed per block) + apply.
// Bt natural row-major. At written PERMUTED (Ap) into A-fragment order so
// k_pass can stage it linearly and ds_read stride-1 (conflict-free):
//   j = S*64 + r*16 + col (S=bj slice), h = ks*32 + q*8 + e
//   float4 chunk dst = S*2048 + (eh)*1024 + (r*4+ks)*64 + q*16 + col,
//   eh = (h>>2)&1. grid 128 x 256.
// ---------------------------------------------------------------------------
__global__ __launch_bounds__(256) void k_fold_apply(const float* __restrict__ gs,
                                                    const float* __restrict__ g1,
                                                    const float* __restrict__ be1,
                                                    const float* __restrict__ A,
                                                    const float* __restrict__ Bm,
                                                    float* __restrict__ Ap,
                                                    float* __restrict__ Bt) {
  __shared__ float sc_s[128], ta_s[128], tb_s[128];
  int t = threadIdx.x;
  if (t < 128) {
    const float inv = 1.f / 1024.f;
    float mA = gs[t] * inv;
    float vA = gs[128 + t] * inv - mA * mA;
    float mB = gs[256 + t] * inv;
    float vB = gs[384 + t] * inv - mB * mB;
    float sc = g1[t] * rsqrtf(vA + vB + EPSV);
    sc_s[t] = sc;
    ta_s[t] = be1[t] - mA * sc;
    tb_s[t] = -mB * sc;
  }
  __syncthreads();
  int idx4 = blockIdx.x * 256 + t;  // 32768 float4 chunks
  int c4 = idx4 & 31;
  float4 sc = ((const float4*)sc_s)[c4];
  float4 ta = ((const float4*)ta_s)[c4];
  float4 tb = ((const float4*)tb_s)[c4];
  float4 a = ((const float4*)A)[idx4];
  float4 b = ((const float4*)Bm)[idx4];
  float4 oa, ob;
  oa.x = fmaf(a.x, sc.x, ta.x); oa.y = fmaf(a.y, sc.y, ta.y);
  oa.z = fmaf(a.z, sc.z, ta.z); oa.w = fmaf(a.w, sc.w, ta.w);
  ob.x = fmaf(b.x, sc.x, tb.x); ob.y = fmaf(b.y, sc.y, tb.y);
  ob.z = fmaf(b.z, sc.z, tb.z); ob.w = fmaf(b.w, sc.w, tb.w);
  // permuted At store
  int j = idx4 >> 5;
  int h4 = c4 << 2;
  int S = j >> 6, r = (j >> 4) & 3, col = j & 15;
  int ks = h4 >> 5, q = (h4 >> 3) & 3, eh = (h4 >> 2) & 1;
  int dst4 = S * 2048 + eh * 1024 + (r * 4 + ks) * 64 + q * 16 + col;
  ((float4*)Ap)[dst4] = oa;
  ((float4*)Bt)[idx4] = ob;
}

// ---------------------------------------------------------------------------
// build fragment: relu(a + Bt_row_slice) -> bf16x8
// ---------------------------------------------------------------------------
__device__ __forceinline__ bf16x8 build2(f32x4 alo, f32x4 ahi,
                                         const float* __restrict__ bp) {
  f32x4 b0 = *(const f32x4*)bp;
  f32x4 b1 = *(const f32x4*)(bp + 4);
  f32x4 z = {0.f, 0.f, 0.f, 0.f};
  f32x4 h0 = __builtin_elementwise_max(alo + b0, z);
  f32x4 h1 = __builtin_elementwise_max(ahi + b1, z);
  f32x8 h = __builtin_shufflevector(h0, h1, 0, 1, 2, 3, 4, 5, 6, 7);
  return __builtin_convertvector(h, bf16x8);
}

// ---------------------------------------------------------------------------
// Main pass. W2 in 128 VGPRs (from permuted w2p, lane-linear coalesced).
// At bj-slice (64 rows, permuted fragment order) + Bt bi-slice (8 rows) in
// LDS via linear global_load_lds. Hot loop = LDS + regs only.
// Block = 4 waves; wave w: i-rows {bi*8+2w,+1}; j: bj*64..+64 (4 subtiles).
// grid 2048 = bi(128) x bj(16). PASS1 -> partials; PASS2 -> logits (fold2
// inlined from sum2).
// ---------------------------------------------------------------------------
template <int PASS>
__global__ __launch_bounds__(256, 2) void k_pass(
    const float* __restrict__ Ap, const float* __restrict__ Bt,
    const unsigned int* __restrict__ w2p, float* __restrict__ partials,
    const float* __restrict__ sum2, const float* __restrict__ g2,
    const float* __restrict__ be2, const float* __restrict__ W3v,
    const float* __restrict__ b3p, float* __restrict__ L) {
  __shared__ float lds[8192 + 1024];  // At slice (32KB) + Bt (4KB); red aliases lds[0..1023]
  float* btl = lds + 8192;
  int t = threadIdx.x;
  int bid = blockIdx.x;
  int bj = bid & 15, bi = bid >> 4;
  int lane = t & 63, w = t >> 6;
  int col = lane & 15, quad = lane >> 4;

  // ---- stage At slice (8192 floats): 32 insts of 1024B, linear ----
  const float* atsrc = Ap + bj * 8192;
#pragma unroll
  for (int it = 0; it < 8; ++it) {
    int g = w * 8 + it;
    __builtin_amdgcn_global_load_lds(
        (const __attribute__((address_space(1))) unsigned int*)(atsrc + g * 256 + lane * 4),
        (__attribute__((address_space(3))) unsigned int*)(lds + g * 256),
        16, 0, 0);
  }
  // ---- stage Bt rows (wave w loads its own 2 rows = 256 floats) ----
  __builtin_amdgcn_global_load_lds(
      (const __attribute__((address_space(1))) unsigned int*)(Bt + (bi * 8 + w * 2) * 128 + lane * 4),
      (__attribute__((address_space(3))) unsigned int*)(btl + w * 256),
      16, 0, 0);

  // ---- preload W2 fragments into 128 VGPRs (coalesced dwordx4) ----
  bf16x8 bw[4][8];
#pragma unroll
  for (int ks = 0; ks < 4; ++ks)
#pragma unroll
    for (int nt = 0; nt < 8; ++nt)
      bw[ks][nt] = *(const bf16x8*)((const __bf16*)w2p + (((ks * 8 + nt) * 64) + lane) * 8);

  float s1[8], s2[8];
  float al[8], uu[8], w3l[8];
  float b3v = 0.f;
  if (PASS == 1) {
#pragma unroll
    for (int nt = 0; nt < 8; ++nt) { s1[nt] = 0.f; s2[nt] = 0.f; }
  } else {
    b3v = b3p[0];
    const float invM = 1.f / (1024.f * 1024.f);
#pragma unroll
    for (int nt = 0; nt < 8; ++nt) {
      int k = nt * 16 + col;
      float mdot = sum2[k] * invM;
      float var = sum2[128 + k] * invM - mdot * mdot;
      float alv = g2[k] * rsqrtf(var + EPSV);
      al[nt] = alv;
      uu[nt] = be2[k] - mdot * alv;
      w3l[nt] = W3v[k];
    }
  }
  __syncthreads();

  const float* bp0 = btl + w * 256;
  const float* bp1 = bp0 + 128;

  for (int s = 0; s < 4; ++s) {
    f32x4 acc[2][8];
#pragma unroll
    for (int mt = 0; mt < 2; ++mt)
#pragma unroll
      for (int nt = 0; nt < 8; ++nt) acc[mt][nt] = (f32x4){0.f, 0.f, 0.f, 0.f};

#pragma unroll
    for (int ks = 0; ks < 4; ++ks) {
      const float* ap = lds + ((s * 4 + ks) * 64 + lane) * 4;
      f32x4 alo = *(const f32x4*)ap;
      f32x4 ahi = *(const f32x4*)(ap + 4096);
      bf16x8 a0 = build2(alo, ahi, bp0 + ks * 32 + quad * 8);
      bf16x8 a1 = build2(alo, ahi, bp1 + ks * 32 + quad * 8);
#pragma unroll
      for (int nt = 0; nt < 8; ++nt) {
        acc[0][nt] = __builtin_amdgcn_mfma_f32_16x16x32_bf16(a0, bw[ks][nt], acc[0][nt], 0, 0, 0);
        acc[1][nt] = __builtin_amdgcn_mfma_f32_16x16x32_bf16(a1, bw[ks][nt], acc[1][nt], 0, 0, 0);
      }
    }

    if (PASS == 1) {
#pragma unroll
      for (int nt = 0; nt < 8; ++nt)
#pragma unroll
        for (int mt = 0; mt < 2; ++mt)
#pragma unroll
          for (int r = 0; r < 4; ++r) {
            float d = acc[mt][nt][r];
            s1[nt] += d;
            s2[nt] = fmaf(d, d, s2[nt]);
          }
    } else {
#pragma unroll
      for (int mt = 0; mt < 2; ++mt) {
        float rsum[4] = {0.f, 0.f, 0.f, 0.f};
#pragma unroll
        for (int nt = 0; nt < 8; ++nt)
#pragma unroll
          for (int r = 0; r < 4; ++r) {
            float h = fmaxf(fmaf(acc[mt][nt][r], al[nt], uu[nt]), 0.f);
            rsum[r] = fmaf(h, w3l[nt], rsum[r]);
          }
#pragma unroll
        for (int r = 0; r < 4; ++r) {
          rsum[r] += __shfl_xor(rsum[r], 1);
          rsum[r] += __shfl_xor(rsum[r], 2);
          rsum[r] += __shfl_xor(rsum[r], 4);
          rsum[r] += __shfl_xor(rsum[r], 8);
        }
        if (col == 0) {
          int i = bi * 8 + w * 2 + mt;
#pragma unroll
          for (int r = 0; r < 4; ++r)
            L[i * 1024 + bj * 64 + s * 16 + quad * 4 + r] = rsum[r] + b3v;
        }
      }
    }
  }

  if (PASS == 1) {
#pragma unroll
    for (int nt = 0; nt < 8; ++nt) {
      s1[nt] += __shfl_xor(s1[nt], 16);
      s1[nt] += __shfl_xor(s1[nt], 32);
      s2[nt] += __shfl_xor(s2[nt], 16);
      s2[nt] += __shfl_xor(s2[nt], 32);
    }
    __syncthreads();  // all At reads done before red aliases lds
    if (lane < 16) {
#pragma unroll
      for (int nt = 0; nt < 8; ++nt) {
        lds[w * 256 + nt * 16 + lane] = s1[nt];
        lds[w * 256 + 128 + nt * 16 + lane] = s2[nt];
      }
    }
    __syncthreads();
    float tot = lds[t] + lds[256 + t] + lds[512 + t] + lds[768 + t];
    partials[bid * 256 + t] = tot;
  }
}

// ---------------------------------------------------------------------------
// K4: reduce pass-1 partials (2048 x 256) -> sum2[256]. grid 128 x 256.
// ---------------------------------------------------------------------------
__global__ __launch_bounds__(256) void k_red_partials(const float* __restrict__ partials,
                                                      float* __restrict__ sum2) {
  int t = threadIdx.x;
  float s = 0.f;
  int r0 = blockIdx.x * 16;
#pragma unroll
  for (int r = 0; r < 16; ++r) s += partials[(r0 + r) * 256 + t];
  atomicAdd(&sum2[t], s);
}

// ---------------------------------------------------------------------------
// K5: adj[i,j] = (i==j) ? 0 : sigmoid(0.5*(L[i,j]+L[j,i])). grid 4096 x 256.
// ---------------------------------------------------------------------------
__global__ __launch_bounds__(256) void k_adj(const float* __restrict__ L,
                                             float* __restrict__ out) {
  int idx = blockIdx.x * 256 + threadIdx.x;
  int i = idx >> 10, j = idx & 1023;
  float a = L[i * 1024 + j];
  float b = L[j * 1024 + i];
  float s = 1.f / (1.f + __expf(-0.5f * (a + b)));
  out[idx] = (i == j) ? 0.f : s;
}

// ---------------------------------------------------------------------------
extern "C" void kernel_launch(void* const* d_in, const int* in_sizes, int n_in,
                              void* d_out, int out_size, void* d_ws, size_t ws_size,
                              hipStream_t stream) {
  const float* x   = (const float*)d_in[0];
  const float* W1  = (const float*)d_in[1];
  const float* W2  = (const float*)d_in[3];
  const float* W3  = (const float*)d_in[5];
  const float* b3  = (const float*)d_in[6];
  const float* g1  = (const float*)d_in[7];
  const float* be1 = (const float*)d_in[8];
  const float* g2  = (const float*)d_in[9];
  const float* be2 = (const float*)d_in[10];

  float* ws = (float*)d_ws;
  float* A        = ws;                 // 131072
  float* Bm       = ws + 131072;        // 131072
  float* Ap       = ws + 262144;        // 131072 (permuted At)
  float* Bt       = ws + 393216;        // 131072
  unsigned int* w2p = (unsigned int*)(ws + 524288);  // 8192 uints
  float* gs       = ws + 532480;        // 512
  float* sum2     = ws + 532992;        // 256   (adjacent to gs: one memset)
  float* partials = ws + 533248;        // 2048*256 = 524288
  float* L        = ws + 1057536;       // 1048576
  float* out      = (float*)d_out;

  hipMemsetAsync(gs, 0, 768 * sizeof(float), stream);  // gs + sum2

  k_ab<<<288, 256, 0, stream>>>(x, W1, W2, A, Bm, gs, w2p);
  k_fold_apply<<<128, 256, 0, stream>>>(gs, g1, be1, A, Bm, Ap, Bt);
  k_pass<1><<<2048, 256, 0, stream>>>(Ap, Bt, w2p, partials, nullptr, nullptr, nullptr, nullptr, nullptr, nullptr);
  k_red_partials<<<128, 256, 0, stream>>>(partials, sum2);
  k_pass<2><<<2048, 256, 0, stream>>>(Ap, Bt, w2p, nullptr, sum2, g2, be2, W3, b3, L);
  k_adj<<<4096, 256, 0, stream>>>(L, out);
}

// Round 6
// 225.317 us; speedup vs baseline: 3.7616x; 1.7047x over previous
//
#include <hip/hip_runtime.h>
#include <hip/hip_bf16.h>

typedef __bf16 bf16x8 __attribute__((ext_vector_type(8)));
typedef float  f32x4  __attribute__((ext_vector_type(4)));
typedef float  f32x8  __attribute__((ext_vector_type(8)));

#define EPSV 1e-5f

// ---------------------------------------------------------------------------
// K1 (grid 288): blocks 0..255: A = x@Wa^T, B = x@Wb^T + stats atomics.
// blocks 256..287: W2 f32 -> bf16 permuted into MFMA B-fragment order:
//   4B chunk c = ((ks*8+nt)*64 + quad*16 + col)*4 + pair
//   elem: k_out = nt*16+col, hch = ks*32+quad*8+pair*2
// ---------------------------------------------------------------------------
__global__ __launch_bounds__(256) void k_ab(const float* __restrict__ x,
                                            const float* __restrict__ W1,
                                            const float* __restrict__ W2,
                                            float* __restrict__ A,
                                            float* __restrict__ Bm,
                                            float* __restrict__ gs,
                                            unsigned int* __restrict__ w2p) {
  __shared__ float xs[4 * 128];
  int t = threadIdx.x;
  if (blockIdx.x >= 256) {  // W2 prep
    int c = (blockIdx.x - 256) * 256 + t;  // 0..8191
    int pair = c & 3;
    int col  = (c >> 2) & 15;
    int quad = (c >> 6) & 3;
    int nt   = (c >> 8) & 7;
    int ks   = (c >> 11) & 3;
    int k = nt * 16 + col;
    int hch = ks * 32 + quad * 8 + pair * 2;
    __bf16 b0 = (__bf16)W2[k * 128 + hch];
    __bf16 b1 = (__bf16)W2[k * 128 + hch + 1];
    unsigned int u0 = *(unsigned short*)&b0, u1 = *(unsigned short*)&b1;
    w2p[c] = u0 | (u1 << 16);
    return;
  }
  int j0 = blockIdx.x * 4;
  for (int idx = t; idx < 512; idx += 256) xs[idx] = x[j0 * 128 + idx];
  __syncthreads();
  int h = t & 127, half = t >> 7;
  const float4* wrow = (const float4*)(W1 + h * 256 + half * 128);
  const float4* xs4 = (const float4*)xs;
  float a0 = 0.f, a1 = 0.f, a2 = 0.f, a3 = 0.f;
#pragma unroll 8
  for (int ch = 0; ch < 32; ++ch) {
    float4 wv = wrow[ch];
    float4 x0 = xs4[ch], x1 = xs4[32 + ch], x2 = xs4[64 + ch], x3 = xs4[96 + ch];
    a0 += wv.x * x0.x + wv.y * x0.y + wv.z * x0.z + wv.w * x0.w;
    a1 += wv.x * x1.x + wv.y * x1.y + wv.z * x1.z + wv.w * x1.w;
    a2 += wv.x * x2.x + wv.y * x2.y + wv.z * x2.z + wv.w * x2.w;
    a3 += wv.x * x3.x + wv.y * x3.y + wv.z * x3.z + wv.w * x3.w;
  }
  float* dst = half ? Bm : A;
  dst[(j0 + 0) * 128 + h] = a0;
  dst[(j0 + 1) * 128 + h] = a1;
  dst[(j0 + 2) * 128 + h] = a2;
  dst[(j0 + 3) * 128 + h] = a3;
  float s = a0 + a1 + a2 + a3;
  float q = a0 * a0 + a1 * a1 + a2 * a2 + a3 * a3;
  atomicAdd(&gs[half * 256 + h], s);
  atomicAdd(&gs[half * 256 + 128 + h], q);
}

// ---------------------------------------------------------------------------
// K2: BN1 fold (recomputed per block) + apply.
// Bt natural row-major. At written PERMUTED (Ap) into A-fragment order so
// k_pass can stage it linearly and ds_read stride-1 (conflict-free):
//   j = S*64 + r*16 + col (S=bj slice), h = ks*32 + q*8 + e
//   float4 chunk dst = S*2048 + (eh)*1024 + (r*4+ks)*64 + q*16 + col,
//   eh = (h>>2)&1. grid 128 x 256.
// ---------------------------------------------------------------------------
__global__ __launch_bounds__(256) void k_fold_apply(const float* __restrict__ gs,
                                                    const float* __restrict__ g1,
                                                    const float* __restrict__ be1,
                                                    const float* __restrict__ A,
                                                    const float* __restrict__ Bm,
                                                    float* __restrict__ Ap,
                                                    float* __restrict__ Bt) {
  __shared__ float sc_s[128], ta_s[128], tb_s[128];
  int t = threadIdx.x;
  if (t < 128) {
    const float inv = 1.f / 1024.f;
    float mA = gs[t] * inv;
    float vA = gs[128 + t] * inv - mA * mA;
    float mB = gs[256 + t] * inv;
    float vB = gs[384 + t] * inv - mB * mB;
    float sc = g1[t] * rsqrtf(vA + vB + EPSV);
    sc_s[t] = sc;
    ta_s[t] = be1[t] - mA * sc;
    tb_s[t] = -mB * sc;
  }
  __syncthreads();
  int idx4 = blockIdx.x * 256 + t;  // 32768 float4 chunks
  int c4 = idx4 & 31;
  float4 sc = ((const float4*)sc_s)[c4];
  float4 ta = ((const float4*)ta_s)[c4];
  float4 tb = ((const float4*)tb_s)[c4];
  float4 a = ((const float4*)A)[idx4];
  float4 b = ((const float4*)Bm)[idx4];
  float4 oa, ob;
  oa.x = fmaf(a.x, sc.x, ta.x); oa.y = fmaf(a.y, sc.y, ta.y);
  oa.z = fmaf(a.z, sc.z, ta.z); oa.w = fmaf(a.w, sc.w, ta.w);
  ob.x = fmaf(b.x, sc.x, tb.x); ob.y = fmaf(b.y, sc.y, tb.y);
  ob.z = fmaf(b.z, sc.z, tb.z); ob.w = fmaf(b.w, sc.w, tb.w);
  // permuted At store
  int j = idx4 >> 5;
  int h4 = c4 << 2;
  int S = j >> 6, r = (j >> 4) & 3, col = j & 15;
  int ks = h4 >> 5, q = (h4 >> 3) & 3, eh = (h4 >> 2) & 1;
  int dst4 = S * 2048 + eh * 1024 + (r * 4 + ks) * 64 + q * 16 + col;
  ((float4*)Ap)[dst4] = oa;
  ((float4*)Bt)[idx4] = ob;
}

// ---------------------------------------------------------------------------
// build fragment: relu(a + Bt_row_slice) -> bf16x8
// ---------------------------------------------------------------------------
__device__ __forceinline__ bf16x8 build2(f32x4 alo, f32x4 ahi,
                                         const float* __restrict__ bp) {
  f32x4 b0 = *(const f32x4*)bp;
  f32x4 b1 = *(const f32x4*)(bp + 4);
  f32x4 z = {0.f, 0.f, 0.f, 0.f};
  f32x4 h0 = __builtin_elementwise_max(alo + b0, z);
  f32x4 h1 = __builtin_elementwise_max(ahi + b1, z);
  f32x8 h = __builtin_shufflevector(h0, h1, 0, 1, 2, 3, 4, 5, 6, 7);
  return __builtin_convertvector(h, bf16x8);
}

// ---------------------------------------------------------------------------
// Main pass. W2 in 128 VGPRs (from permuted w2p, lane-linear coalesced).
// At bj-slice (64 rows, permuted fragment order) + Bt bi-slice (8 rows) in
// LDS via linear global_load_lds. Hot loop = LDS + regs only.
// Block = 4 waves; wave w: i-rows {bi*8+2w,+1}; j: bj*64..+64 (4 subtiles).
// grid 2048 = bi(128) x bj(16). PASS1 -> partials; PASS2 -> logits (fold2
// inlined from sum2).
// NOTE: plain __launch_bounds__(256) — min-waves clamps (,2)/(,3)/(,4) all
// made the allocator split the unified VGPR/AGPR file and spill 100s of MB
// to scratch (R3/R4/R5 evidence: WRITE_SIZE 200-300 MB). Natural allocation
// is ~176-200 regs, no spill, 2 waves/SIMD.
// ---------------------------------------------------------------------------
template <int PASS>
__global__ __launch_bounds__(256) void k_pass(
    const float* __restrict__ Ap, const float* __restrict__ Bt,
    const unsigned int* __restrict__ w2p, float* __restrict__ partials,
    const float* __restrict__ sum2, const float* __restrict__ g2,
    const float* __restrict__ be2, const float* __restrict__ W3v,
    const float* __restrict__ b3p, float* __restrict__ L) {
  __shared__ float lds[8192 + 1024];  // At slice (32KB) + Bt (4KB); red aliases lds[0..1023]
  float* btl = lds + 8192;
  int t = threadIdx.x;
  int bid = blockIdx.x;
  int bj = bid & 15, bi = bid >> 4;
  int lane = t & 63, w = t >> 6;
  int col = lane & 15, quad = lane >> 4;

  // ---- stage At slice (8192 floats): 32 insts of 1024B, linear ----
  const float* atsrc = Ap + bj * 8192;
#pragma unroll
  for (int it = 0; it < 8; ++it) {
    int g = w * 8 + it;
    __builtin_amdgcn_global_load_lds(
        (const __attribute__((address_space(1))) unsigned int*)(atsrc + g * 256 + lane * 4),
        (__attribute__((address_space(3))) unsigned int*)(lds + g * 256),
        16, 0, 0);
  }
  // ---- stage Bt rows (wave w loads its own 2 rows = 256 floats) ----
  __builtin_amdgcn_global_load_lds(
      (const __attribute__((address_space(1))) unsigned int*)(Bt + (bi * 8 + w * 2) * 128 + lane * 4),
      (__attribute__((address_space(3))) unsigned int*)(btl + w * 256),
      16, 0, 0);

  // ---- preload W2 fragments into 128 VGPRs (coalesced dwordx4) ----
  bf16x8 bw[4][8];
#pragma unroll
  for (int ks = 0; ks < 4; ++ks)
#pragma unroll
    for (int nt = 0; nt < 8; ++nt)
      bw[ks][nt] = *(const bf16x8*)((const __bf16*)w2p + (((ks * 8 + nt) * 64) + lane) * 8);

  float s1[8], s2[8];
  float al[8], uu[8], w3l[8];
  float b3v = 0.f;
  if (PASS == 1) {
#pragma unroll
    for (int nt = 0; nt < 8; ++nt) { s1[nt] = 0.f; s2[nt] = 0.f; }
  } else {
    b3v = b3p[0];
    const float invM = 1.f / (1024.f * 1024.f);
#pragma unroll
    for (int nt = 0; nt < 8; ++nt) {
      int k = nt * 16 + col;
      float mdot = sum2[k] * invM;
      float var = sum2[128 + k] * invM - mdot * mdot;
      float alv = g2[k] * rsqrtf(var + EPSV);
      al[nt] = alv;
      uu[nt] = be2[k] - mdot * alv;
      w3l[nt] = W3v[k];
    }
  }
  __syncthreads();

  const float* bp0 = btl + w * 256;
  const float* bp1 = bp0 + 128;

  for (int s = 0; s < 4; ++s) {
    f32x4 acc[2][8];
#pragma unroll
    for (int mt = 0; mt < 2; ++mt)
#pragma unroll
      for (int nt = 0; nt < 8; ++nt) acc[mt][nt] = (f32x4){0.f, 0.f, 0.f, 0.f};

#pragma unroll
    for (int ks = 0; ks < 4; ++ks) {
      const float* ap = lds + ((s * 4 + ks) * 64 + lane) * 4;
      f32x4 alo = *(const f32x4*)ap;
      f32x4 ahi = *(const f32x4*)(ap + 4096);
      bf16x8 a0 = build2(alo, ahi, bp0 + ks * 32 + quad * 8);
      bf16x8 a1 = build2(alo, ahi, bp1 + ks * 32 + quad * 8);
#pragma unroll
      for (int nt = 0; nt < 8; ++nt) {
        acc[0][nt] = __builtin_amdgcn_mfma_f32_16x16x32_bf16(a0, bw[ks][nt], acc[0][nt], 0, 0, 0);
        acc[1][nt] = __builtin_amdgcn_mfma_f32_16x16x32_bf16(a1, bw[ks][nt], acc[1][nt], 0, 0, 0);
      }
    }

    if (PASS == 1) {
#pragma unroll
      for (int nt = 0; nt < 8; ++nt)
#pragma unroll
        for (int mt = 0; mt < 2; ++mt)
#pragma unroll
          for (int r = 0; r < 4; ++r) {
            float d = acc[mt][nt][r];
            s1[nt] += d;
            s2[nt] = fmaf(d, d, s2[nt]);
          }
    } else {
#pragma unroll
      for (int mt = 0; mt < 2; ++mt) {
        float rsum[4] = {0.f, 0.f, 0.f, 0.f};
#pragma unroll
        for (int nt = 0; nt < 8; ++nt)
#pragma unroll
          for (int r = 0; r < 4; ++r) {
            float h = fmaxf(fmaf(acc[mt][nt][r], al[nt], uu[nt]), 0.f);
            rsum[r] = fmaf(h, w3l[nt], rsum[r]);
          }
#pragma unroll
        for (int r = 0; r < 4; ++r) {
          rsum[r] += __shfl_xor(rsum[r], 1);
          rsum[r] += __shfl_xor(rsum[r], 2);
          rsum[r] += __shfl_xor(rsum[r], 4);
          rsum[r] += __shfl_xor(rsum[r], 8);
        }
        if (col == 0) {
          int i = bi * 8 + w * 2 + mt;
#pragma unroll
          for (int r = 0; r < 4; ++r)
            L[i * 1024 + bj * 64 + s * 16 + quad * 4 + r] = rsum[r] + b3v;
        }
      }
    }
  }

  if (PASS == 1) {
#pragma unroll
    for (int nt = 0; nt < 8; ++nt) {
      s1[nt] += __shfl_xor(s1[nt], 16);
      s1[nt] += __shfl_xor(s1[nt], 32);
      s2[nt] += __shfl_xor(s2[nt], 16);
      s2[nt] += __shfl_xor(s2[nt], 32);
    }
    __syncthreads();  // all At reads done before red aliases lds
    if (lane < 16) {
#pragma unroll
      for (int nt = 0; nt < 8; ++nt) {
        lds[w * 256 + nt * 16 + lane] = s1[nt];
        lds[w * 256 + 128 + nt * 16 + lane] = s2[nt];
      }
    }
    __syncthreads();
    float tot = lds[t] + lds[256 + t] + lds[512 + t] + lds[768 + t];
    partials[bid * 256 + t] = tot;
  }
}

// ---------------------------------------------------------------------------
// K4: reduce pass-1 partials (2048 x 256) -> sum2[256]. grid 128 x 256.
// ---------------------------------------------------------------------------
__global__ __launch_bounds__(256) void k_red_partials(const float* __restrict__ partials,
                                                      float* __restrict__ sum2) {
  int t = threadIdx.x;
  float s = 0.f;
  int r0 = blockIdx.x * 16;
#pragma unroll
  for (int r = 0; r < 16; ++r) s += partials[(r0 + r) * 256 + t];
  atomicAdd(&sum2[t], s);
}

// ---------------------------------------------------------------------------
// K5: adj[i,j] = (i==j) ? 0 : sigmoid(0.5*(L[i,j]+L[j,i])). grid 4096 x 256.
// ---------------------------------------------------------------------------
__global__ __launch_bounds__(256) void k_adj(const float* __restrict__ L,
                                             float* __restrict__ out) {
  int idx = blockIdx.x * 256 + threadIdx.x;
  int i = idx >> 10, j = idx & 1023;
  float a = L[i * 1024 + j];
  float b = L[j * 1024 + i];
  float s = 1.f / (1.f + __expf(-0.5f * (a + b)));
  out[idx] = (i == j) ? 0.f : s;
}

// ---------------------------------------------------------------------------
extern "C" void kernel_launch(void* const* d_in, const int* in_sizes, int n_in,
                              void* d_out, int out_size, void* d_ws, size_t ws_size,
                              hipStream_t stream) {
  const float* x   = (const float*)d_in[0];
  const float* W1  = (const float*)d_in[1];
  const float* W2  = (const float*)d_in[3];
  const float* W3  = (const float*)d_in[5];
  const float* b3  = (const float*)d_in[6];
  const float* g1  = (const float*)d_in[7];
  const float* be1 = (const float*)d_in[8];
  const float* g2  = (const float*)d_in[9];
  const float* be2 = (const float*)d_in[10];

  float* ws = (float*)d_ws;
  float* A        = ws;                 // 131072
  float* Bm       = ws + 131072;        // 131072
  float* Ap       = ws + 262144;        // 131072 (permuted At)
  float* Bt       = ws + 393216;        // 131072
  unsigned int* w2p = (unsigned int*)(ws + 524288);  // 8192 uints
  float* gs       = ws + 532480;        // 512
  float* sum2     = ws + 532992;        // 256   (adjacent to gs: one memset)
  float* partials = ws + 533248;        // 2048*256 = 524288
  float* L        = ws + 1057536;       // 1048576
  float* out      = (float*)d_out;

  hipMemsetAsync(gs, 0, 768 * sizeof(float), stream);  // gs + sum2

  k_ab<<<288, 256, 0, stream>>>(x, W1, W2, A, Bm, gs, w2p);
  k_fold_apply<<<128, 256, 0, stream>>>(gs, g1, be1, A, Bm, Ap, Bt);
  k_pass<1><<<2048, 256, 0, stream>>>(Ap, Bt, w2p, partials, nullptr, nullptr, nullptr, nullptr, nullptr, nullptr);
  k_red_partials<<<128, 256, 0, stream>>>(partials, sum2);
  k_pass<2><<<2048, 256, 0, stream>>>(Ap, Bt, w2p, nullptr, sum2, g2, be2, W3, b3, L);
  k_adj<<<4096, 256, 0, stream>>>(L, out);
}